// Round 1
// baseline (1498.707 us; speedup 1.0000x reference)
//
#include <hip/hip_runtime.h>
#include <hip/hip_bf16.h>

#define Bb 4
#define Cc 96
#define Hh 256
#define Ww 512
#define OC 192
#define HO 128
#define WO 256
#define Gg 16
#define CPG 6
#define OCPB 8
#define NOCB (OC / OCPB)

// Kernel A: conv3x3 stride2 pad1 (96->192) + BN(eval) + LeakyReLU(0.1) -> y in ws
// block = (b, oh, ocq): 256 threads = ow 0..255, each thread accumulates 8 oc.
__global__ __launch_bounds__(256) void conv_bn_lrelu(
        const float* __restrict__ x, const float* __restrict__ w1,
        const float* __restrict__ gamma, const float* __restrict__ beta,
        float* __restrict__ y) {
    __shared__ float wl[Cc * 9][OCPB];  // 27648 B
    const int bid = blockIdx.x;
    const int ocq = bid % NOCB;
    const int oh  = (bid / NOCB) % HO;
    const int b   = bid / (NOCB * HO);
    const int oc0 = ocq * OCPB;

    // stage weights: wl[ic*9 + k][j] = w1[(oc0+j)*864 + ic*9 + k]
    for (int t = threadIdx.x; t < Cc * 9 * OCPB; t += 256) {
        const int j = t % OCPB;
        const int r = t / OCPB;
        wl[r][j] = w1[(oc0 + j) * (Cc * 9) + r];
    }
    __syncthreads();

    const int ow  = threadIdx.x;
    const int iw0 = 2 * ow - 1;
    float acc[OCPB];
#pragma unroll
    for (int j = 0; j < OCPB; ++j) acc[j] = 0.f;

    for (int ic = 0; ic < Cc; ++ic) {
        const float* xp = x + ((size_t)(b * Cc + ic) * Hh) * Ww;
#pragma unroll
        for (int kh = 0; kh < 3; ++kh) {
            const int ih = 2 * oh - 1 + kh;
            if (ih < 0 || ih >= Hh) continue;  // only oh==0,kh==0 in practice
            const float* row = xp + (size_t)ih * Ww;
            float xv[3];
            xv[0] = (iw0 >= 0) ? row[iw0] : 0.f;
            xv[1] = row[iw0 + 1];
            xv[2] = row[iw0 + 2];
#pragma unroll
            for (int kw = 0; kw < 3; ++kw) {
                const float xvv = xv[kw];
                const float* wr = &wl[ic * 9 + kh * 3 + kw][0];
#pragma unroll
                for (int j = 0; j < OCPB; ++j) acc[j] += xvv * wr[j];
            }
        }
    }

    const float bnr = 1.0f / sqrtf(1.0f + 1e-5f);
#pragma unroll
    for (int j = 0; j < OCPB; ++j) {
        const int oc = oc0 + j;
        float v = acc[j] * (gamma[oc] * bnr) + beta[oc];
        v = (v >= 0.f) ? v : 0.1f * v;
        y[((size_t)(b * OC + oc) * HO + oh) * WO + ow] = v;
    }
}

// Kernel B: 1x1 conv (192 -> 9 logits for group g) + softmax + unfold-weighted sum.
// block = (b, g, oh): 256 threads = ow. Each thread writes 6 output channels.
__global__ __launch_bounds__(256) void mask_apply(
        const float* __restrict__ x, const float* __restrict__ y,
        const float* __restrict__ w2, float* __restrict__ out) {
    __shared__ float w2l[OC * 9];  // [c][k], 6912 B
    const int bid = blockIdx.x;
    const int g  = bid % Gg;
    const int oh = (bid / Gg) % HO;
    const int b  = bid / (Gg * HO);

    for (int t = threadIdx.x; t < OC * 9; t += 256) {
        const int k = t % 9;
        const int c = t / 9;
        w2l[t] = w2[(g * 9 + k) * OC + c];
    }
    __syncthreads();

    const int ow = threadIdx.x;
    float logit[9];
#pragma unroll
    for (int k = 0; k < 9; ++k) logit[k] = 0.f;

    const float* yp = y + ((size_t)b * OC * HO + oh) * WO + ow;
    for (int c = 0; c < OC; ++c) {
        const float yv = yp[(size_t)c * HO * WO];
        const float* wr = &w2l[c * 9];
#pragma unroll
        for (int k = 0; k < 9; ++k) logit[k] += yv * wr[k];
    }

    // softmax over the 9 taps
    float m = logit[0];
#pragma unroll
    for (int k = 1; k < 9; ++k) m = fmaxf(m, logit[k]);
    float p[9], s = 0.f;
#pragma unroll
    for (int k = 0; k < 9; ++k) { p[k] = __expf(logit[k] - m); s += p[k]; }
    const float inv = 1.f / s;
#pragma unroll
    for (int k = 0; k < 9; ++k) p[k] *= inv;

    // weighted sum of unfolded patches: out[b][i*G+g][oh][ow]
    const int iw0 = 2 * ow - 1;
    const int ih0 = 2 * oh - 1;
#pragma unroll
    for (int i = 0; i < CPG; ++i) {
        const int cc = i * Gg + g;
        const float* xp = x + ((size_t)(b * Cc + cc) * Hh) * Ww;
        float acc = 0.f;
#pragma unroll
        for (int kh = 0; kh < 3; ++kh) {
            const int ih = ih0 + kh;
            if (ih < 0) continue;
            const float* row = xp + (size_t)ih * Ww;
#pragma unroll
            for (int kw = 0; kw < 3; ++kw) {
                const int iw = iw0 + kw;
                if (iw < 0) continue;
                acc += p[kh * 3 + kw] * row[iw];
            }
        }
        out[((size_t)(b * Cc + cc) * HO + oh) * WO + ow] = acc;
    }
}

extern "C" void kernel_launch(void* const* d_in, const int* in_sizes, int n_in,
                              void* d_out, int out_size, void* d_ws, size_t ws_size,
                              hipStream_t stream) {
    const float* x     = (const float*)d_in[0];
    const float* w1    = (const float*)d_in[1];
    const float* gamma = (const float*)d_in[2];
    const float* beta  = (const float*)d_in[3];
    const float* w2    = (const float*)d_in[4];
    float* out = (float*)d_out;
    float* y   = (float*)d_ws;  // needs 192*128*256*4*4 = 100,663,296 B

    conv_bn_lrelu<<<Bb * HO * NOCB, 256, 0, stream>>>(x, w1, gamma, beta, y);
    mask_apply<<<Bb * HO * Gg, 256, 0, stream>>>(x, y, w2, out);
}

// Round 2
// 600.515 us; speedup vs baseline: 2.4957x; 2.4957x over previous
//
#include <hip/hip_runtime.h>
#include <hip/hip_bf16.h>

#define Bb 4
#define Cc 96
#define Hh 256
#define Ww 512
#define OC 192
#define HO 128
#define WO 256
#define Gg 16
#define CPG 6

typedef __attribute__((ext_vector_type(4))) float f32x4;
typedef __attribute__((ext_vector_type(8))) short bf16x8;
typedef __attribute__((ext_vector_type(4))) short bf16x4;

static __device__ __forceinline__ ushort f2b(float f) {
    __hip_bfloat16 h = __float2bfloat16(f);
    return *reinterpret_cast<ushort*>(&h);
}
static __device__ __forceinline__ float b2f(ushort u) {
    unsigned int v = ((unsigned int)u) << 16;
    return __builtin_bit_cast(float, v);
}

// ---------------------------------------------------------------------------
// Pack w1 (fp32, [192][96][3][3]) into MFMA-fragment-ordered bf16:
// k = chunk*288 + tap*32 + icw  (chunk=ic/32, tap=kh*3+kw, icw=ic%32)
// slot (k0, mf, lane, j):  m = mf*16 + (lane&15),
//                          klocal = (lane>>4)*4 + (j&3) + 16*(j>>2)
// ---------------------------------------------------------------------------
__global__ __launch_bounds__(64) void pack_w1(const float* __restrict__ w1,
                                              ushort* __restrict__ apack) {
    const int blk = blockIdx.x;      // 27*12
    const int k0 = blk / 12;
    const int mf = blk % 12;
    const int lane = threadIdx.x;
    const int m = mf * 16 + (lane & 15);
    const int chunk = k0 / 9;
    const int tap = k0 % 9;
    ushort* dst = apack + (((size_t)(k0 * 12 + mf) * 64) + lane) * 8;
#pragma unroll
    for (int j = 0; j < 8; ++j) {
        const int klocal = ((lane >> 4) * 4) + (j & 3) + 16 * (j >> 2);
        const int ic = chunk * 32 + klocal;
        dst[j] = f2b(w1[(size_t)(m * Cc + ic) * 9 + tap]);
    }
}

// ---------------------------------------------------------------------------
// Implicit-GEMM conv3x3 s2 p1 (96->192) + BN + LeakyReLU, bf16 MFMA.
// Block: 256 thr (4 waves). Tile: M=192 oc, N=128 ow, all K. y out in bf16.
// ---------------------------------------------------------------------------
__global__ __launch_bounds__(256, 2) void conv_mfma(
        const float* __restrict__ x, const ushort* __restrict__ apack,
        const float* __restrict__ gamma, const float* __restrict__ beta,
        ushort* __restrict__ y) {
    __shared__ __align__(16) ushort xl[3][260][40];  // [kh][col][ic%32], 62400 B
    __shared__ float sc[OC], bi[OC];

    const int bid = blockIdx.x;
    const int owt = bid & 1;
    const int oh = (bid >> 1) & 127;
    const int b = bid >> 8;
    const int ow0 = owt * 128;
    const int tid = threadIdx.x;
    const int w = tid >> 6;
    const int lane = tid & 63;

    if (tid < OC) {
        const float bnr = 1.0f / sqrtf(1.0f + 1e-5f);
        sc[tid] = gamma[tid] * bnr;
        bi[tid] = beta[tid];
    }

    f32x4 acc[12][2];
#pragma unroll
    for (int mf = 0; mf < 12; ++mf)
#pragma unroll
        for (int nf = 0; nf < 2; ++nf) acc[mf][nf] = (f32x4){0.f, 0.f, 0.f, 0.f};

    for (int chunk = 0; chunk < 3; ++chunk) {
        __syncthreads();  // protect xl from previous chunk's readers
        // stage 32 channels x 3 rows x 257 cols as bf16 (zero-pad halo)
        for (int idx = tid; idx < 96 * 260; idx += 256) {
            const int p = idx / 260;
            const int col = idx - p * 260;
            const int ch = p / 3;
            const int row = p - ch * 3;
            const int ih = 2 * oh - 1 + row;
            const int gcol = 2 * ow0 - 1 + col;
            float v = 0.f;
            if (col < 257 && ih >= 0 && gcol >= 0 && gcol < Ww)
                v = x[((size_t)((b * Cc + chunk * 32 + ch)) * Hh + ih) * Ww + gcol];
            xl[row][col][ch] = f2b(v);
        }
        __syncthreads();

#pragma unroll
        for (int tap = 0; tap < 9; ++tap) {
            const int kh = tap / 3, kw = tap % 3;
            const int k0 = chunk * 9 + tap;
            // A fragments (L2-resident packed weights)
            bf16x8 af[12];
            const ushort* ap = apack + (((size_t)(k0 * 12) * 64) + lane) * 8;
#pragma unroll
            for (int mf = 0; mf < 12; ++mf)
                af[mf] = *reinterpret_cast<const bf16x8*>(ap + (size_t)mf * 64 * 8);
            // B fragments from LDS rows (two K=16 halves)
            bf16x8 bfr[2];
#pragma unroll
            for (int nf = 0; nf < 2; ++nf) {
                const int n = w * 32 + nf * 16 + (lane & 15);
                const int cl = 2 * n + kw;
                const ushort* bp = &xl[kh][cl][(lane >> 4) * 4];
                bf16x4 lo = *reinterpret_cast<const bf16x4*>(bp);
                bf16x4 hi = *reinterpret_cast<const bf16x4*>(bp + 16);
                bf16x8 t;
                t[0] = lo[0]; t[1] = lo[1]; t[2] = lo[2]; t[3] = lo[3];
                t[4] = hi[0]; t[5] = hi[1]; t[6] = hi[2]; t[7] = hi[3];
                bfr[nf] = t;
            }
#pragma unroll
            for (int mf = 0; mf < 12; ++mf)
#pragma unroll
                for (int nf = 0; nf < 2; ++nf)
                    acc[mf][nf] = __builtin_amdgcn_mfma_f32_16x16x32_bf16(
                        af[mf], bfr[nf], acc[mf][nf], 0, 0, 0);
        }
    }

    // epilogue: BN + LeakyReLU, store bf16 y
#pragma unroll
    for (int mf = 0; mf < 12; ++mf)
#pragma unroll
        for (int nf = 0; nf < 2; ++nf)
#pragma unroll
            for (int r = 0; r < 4; ++r) {
                const int oc = mf * 16 + (lane >> 4) * 4 + r;
                const int ow = ow0 + w * 32 + nf * 16 + (lane & 15);
                float v = acc[mf][nf][r] * sc[oc] + bi[oc];
                v = (v >= 0.f) ? v : 0.1f * v;
                y[((size_t)(b * OC + oc) * HO + oh) * WO + ow] = f2b(v);
            }
}

// ---------------------------------------------------------------------------
// 1x1 conv (192->9 logits, group g) + softmax + unfold-weighted sum.
// ---------------------------------------------------------------------------
__global__ __launch_bounds__(256) void mask_apply(
        const float* __restrict__ x, const ushort* __restrict__ y,
        const float* __restrict__ w2, float* __restrict__ out) {
    __shared__ float w2l[OC * 9];
    const int bid = blockIdx.x;
    const int g = bid % Gg;
    const int oh = (bid / Gg) % HO;
    const int b = bid / (Gg * HO);

    for (int t = threadIdx.x; t < OC * 9; t += 256) {
        const int k = t % 9;
        const int c = t / 9;
        w2l[t] = w2[(g * 9 + k) * OC + c];
    }
    __syncthreads();

    const int ow = threadIdx.x;
    float logit[9];
#pragma unroll
    for (int k = 0; k < 9; ++k) logit[k] = 0.f;

    const ushort* yp = y + ((size_t)b * OC * HO + oh) * WO + ow;
    for (int c = 0; c < OC; ++c) {
        const float yv = b2f(yp[(size_t)c * HO * WO]);
        const float* wr = &w2l[c * 9];
#pragma unroll
        for (int k = 0; k < 9; ++k) logit[k] += yv * wr[k];
    }

    float m = logit[0];
#pragma unroll
    for (int k = 1; k < 9; ++k) m = fmaxf(m, logit[k]);
    float p[9], s = 0.f;
#pragma unroll
    for (int k = 0; k < 9; ++k) { p[k] = __expf(logit[k] - m); s += p[k]; }
    const float inv = 1.f / s;
#pragma unroll
    for (int k = 0; k < 9; ++k) p[k] *= inv;

    const int iw0 = 2 * ow - 1;
    const int ih0 = 2 * oh - 1;
#pragma unroll
    for (int i = 0; i < CPG; ++i) {
        const int cc = i * Gg + g;
        const float* xp = x + ((size_t)(b * Cc + cc) * Hh) * Ww;
        float acc = 0.f;
#pragma unroll
        for (int kh = 0; kh < 3; ++kh) {
            const int ih = ih0 + kh;
            if (ih < 0) continue;
            const float* row = xp + (size_t)ih * Ww;
#pragma unroll
            for (int kw = 0; kw < 3; ++kw) {
                const int iw = iw0 + kw;
                if (iw < 0) continue;
                acc += p[kh * 3 + kw] * row[iw];
            }
        }
        out[((size_t)(b * Cc + cc) * HO + oh) * WO + ow] = acc;
    }
}

extern "C" void kernel_launch(void* const* d_in, const int* in_sizes, int n_in,
                              void* d_out, int out_size, void* d_ws, size_t ws_size,
                              hipStream_t stream) {
    const float* x     = (const float*)d_in[0];
    const float* w1    = (const float*)d_in[1];
    const float* gamma = (const float*)d_in[2];
    const float* beta  = (const float*)d_in[3];
    const float* w2    = (const float*)d_in[4];
    float* out = (float*)d_out;

    ushort* y     = (ushort*)d_ws;                              // 50,331,648 B
    ushort* apack = (ushort*)((char*)d_ws + (size_t)50331648);  // +331,776 B

    pack_w1<<<27 * 12, 64, 0, stream>>>(w1, apack);
    conv_mfma<<<Bb * HO * 2, 256, 0, stream>>>(x, apack, gamma, beta, y);
    mask_apply<<<Bb * HO * Gg, 256, 0, stream>>>(x, y, w2, out);
}

// Round 3
// 315.485 us; speedup vs baseline: 4.7505x; 1.9035x over previous
//
#include <hip/hip_runtime.h>
#include <hip/hip_bf16.h>

#define Bb 4
#define Cc 96
#define Hh 256
#define Ww 512
#define OC 192
#define HO 128
#define WO 256
#define Gg 16
#define CPG 6

typedef __attribute__((ext_vector_type(4))) float f32x4;
typedef __attribute__((ext_vector_type(8))) short bf16x8;
typedef __attribute__((ext_vector_type(4))) short bf16x4;

static __device__ __forceinline__ ushort f2b(float f) {
    __hip_bfloat16 h = __float2bfloat16(f);
    return *reinterpret_cast<ushort*>(&h);
}
static __device__ __forceinline__ float b2f(ushort u) {
    unsigned int v = ((unsigned int)u) << 16;
    return __builtin_bit_cast(float, v);
}

// ---------------------------------------------------------------------------
// Pack w1 (fp32, [192][96][3][3]) into MFMA-fragment-ordered bf16 (UNCHANGED
// from R2 — this mapping is HW-verified):
// k = chunk*288 + tap*32 + icw ; slot (k0, mf, lane, j): m = mf*16+(lane&15),
// klocal = (lane>>4)*4 + (j&3) + 16*(j>>2)
// ---------------------------------------------------------------------------
__global__ __launch_bounds__(64) void pack_w1(const float* __restrict__ w1,
                                              ushort* __restrict__ apack) {
    const int blk = blockIdx.x;      // 27*12
    const int k0 = blk / 12;
    const int mf = blk % 12;
    const int lane = threadIdx.x;
    const int m = mf * 16 + (lane & 15);
    const int chunk = k0 / 9;
    const int tap = k0 % 9;
    ushort* dst = apack + (((size_t)(k0 * 12 + mf) * 64) + lane) * 8;
#pragma unroll
    for (int j = 0; j < 8; ++j) {
        const int klocal = ((lane >> 4) * 4) + (j & 3) + 16 * (j >> 2);
        const int ic = chunk * 32 + klocal;
        dst[j] = f2b(w1[(size_t)(m * Cc + ic) * 9 + tap]);
    }
}

// ---------------------------------------------------------------------------
// Implicit-GEMM conv3x3 s2 p1 (96->192) + BN + LeakyReLU, bf16 MFMA.
// Block: 256 thr (4 waves, 2M x 2N). Tile: M=192 oc, N=128 ow. y out bf16.
// LDS x tile: [row3][par2][col128][ic32] bf16, 16B-unit XOR swizzle oct^(col&3).
// ---------------------------------------------------------------------------
#define XL_HALO (3 * 2 * 128 * 32)              // ushort offset of halo area
__global__ __launch_bounds__(256, 2) void conv_mfma(
        const float* __restrict__ x, const ushort* __restrict__ apack,
        const float* __restrict__ gamma, const float* __restrict__ beta,
        ushort* __restrict__ y) {
    __shared__ __align__(16) ushort xl[XL_HALO + 3 * 32];  // 49344 B
    __shared__ float sc[OC], bi[OC];

    const int bid = blockIdx.x;
    const int owt = bid & 1;
    const int oh = (bid >> 1) & 127;
    const int b = bid >> 8;
    const int ow0 = owt * 128;
    const int tid = threadIdx.x;
    const int wid = tid >> 6;
    const int wm = wid & 1;        // M half: oc base = wm*96
    const int wn = wid >> 1;       // N half: ow base = wn*64
    const int lane = tid & 63;
    const int r = lane & 15;
    const int q = lane >> 4;

    if (tid < OC) {
        const float bnr = 1.0f / sqrtf(1.0f + 1e-5f);
        sc[tid] = gamma[tid] * bnr;
        bi[tid] = beta[tid];
    }

    f32x4 acc[6][4];
#pragma unroll
    for (int mf = 0; mf < 6; ++mf)
#pragma unroll
        for (int nf = 0; nf < 4; ++nf) acc[mf][nf] = (f32x4){0.f, 0.f, 0.f, 0.f};

    const size_t chs = (size_t)Hh * Ww;

    for (int chunk = 0; chunk < 3; ++chunk) {
        __syncthreads();  // protect xl from previous chunk's readers
        // ---- staging: 3072 b128 writes = 256 thr x 12 iters (pow2 decompose)
        const int icc = chunk * 32;
#pragma unroll
        for (int it = 0; it < 12; ++it) {
            const int g = tid + (it << 8);
            const int oct = g & 3;
            const int col = (g >> 2) & 127;
            const int par = (g >> 9) & 1;
            const int row = g >> 10;                 // 0..2
            const int ih = 2 * oh - 1 + row;
            const int gcol = 2 * (ow0 + col) + par;
            float v[8];
            if (ih >= 0) {
                const float* xp = x + ((size_t)(b * Cc + icc + (oct << 3)) * Hh + ih) * Ww + gcol;
#pragma unroll
                for (int j = 0; j < 8; ++j) v[j] = xp[(size_t)j * chs];
            } else {
#pragma unroll
                for (int j = 0; j < 8; ++j) v[j] = 0.f;
            }
            bf16x8 u;
#pragma unroll
            for (int j = 0; j < 8; ++j) u[j] = (short)f2b(v[j]);
            const int du = ((row * 2 + par) * 128 + col) * 32 + ((oct ^ (col & 3)) << 3);
            *reinterpret_cast<bf16x8*>(xl + du) = u;
        }
        // ---- halo col: o-local = -1  (gcol = 2*ow0 - 1), linear layout
        if (tid < 12) {
            const int oct = tid & 3;
            const int row = tid >> 2;
            const int ih = 2 * oh - 1 + row;
            const int gcol = 2 * ow0 - 1;
            float v[8];
            if (ih >= 0 && gcol >= 0) {
                const float* xp = x + ((size_t)(b * Cc + icc + (oct << 3)) * Hh + ih) * Ww + gcol;
#pragma unroll
                for (int j = 0; j < 8; ++j) v[j] = xp[(size_t)j * chs];
            } else {
#pragma unroll
                for (int j = 0; j < 8; ++j) v[j] = 0.f;
            }
            bf16x8 u;
#pragma unroll
            for (int j = 0; j < 8; ++j) u[j] = (short)f2b(v[j]);
            *reinterpret_cast<bf16x8*>(xl + XL_HALO + row * 32 + (oct << 3)) = u;
        }
        __syncthreads();

        // ---- compute: 9 taps x (6 A-frags, 4 B-frags, 24 MFMA)
#pragma unroll
        for (int tap = 0; tap < 9; ++tap) {
            const int kh = tap / 3, kw = tap % 3;
            const int par = (kw == 1) ? 0 : 1;
            const int cb = (kw == 0) ? -1 : 0;
            const int k0 = chunk * 9 + tap;

            bf16x8 af[6];
            const ushort* ap = apack + (((size_t)(k0 * 12 + wm * 6) * 64) + lane) * 8;
#pragma unroll
            for (int mf = 0; mf < 6; ++mf)
                af[mf] = *reinterpret_cast<const bf16x8*>(ap + (size_t)mf * 64 * 8);

            bf16x8 bfr[4];
#pragma unroll
            for (int nf = 0; nf < 4; ++nf) {
                const int n = wn * 64 + nf * 16 + r;
                const int colc = n + cb;
                int lo_u, hi_u;
                if (colc >= 0) {
                    const int bu = ((kh * 2 + par) * 128 + colc) * 32;
                    const int sw = colc & 3;
                    lo_u = bu + ((((q >> 1)) ^ sw) << 3) + ((q & 1) << 2);
                    hi_u = bu + (((2 + (q >> 1)) ^ sw) << 3) + ((q & 1) << 2);
                } else {
                    const int bu = XL_HALO + kh * 32;
                    lo_u = bu + (q << 2);
                    hi_u = bu + 16 + (q << 2);
                }
                bf16x4 lo = *reinterpret_cast<const bf16x4*>(xl + lo_u);
                bf16x4 hi = *reinterpret_cast<const bf16x4*>(xl + hi_u);
                bf16x8 t;
                t[0] = lo[0]; t[1] = lo[1]; t[2] = lo[2]; t[3] = lo[3];
                t[4] = hi[0]; t[5] = hi[1]; t[6] = hi[2]; t[7] = hi[3];
                bfr[nf] = t;
            }
#pragma unroll
            for (int mf = 0; mf < 6; ++mf)
#pragma unroll
                for (int nf = 0; nf < 4; ++nf)
                    acc[mf][nf] = __builtin_amdgcn_mfma_f32_16x16x32_bf16(
                        af[mf], bfr[nf], acc[mf][nf], 0, 0, 0);
        }
    }

    // ---- epilogue: BN + LeakyReLU, store bf16 y
#pragma unroll
    for (int mf = 0; mf < 6; ++mf)
#pragma unroll
        for (int nf = 0; nf < 4; ++nf)
#pragma unroll
            for (int rr = 0; rr < 4; ++rr) {
                const int oc = wm * 96 + mf * 16 + q * 4 + rr;
                const int ow = ow0 + wn * 64 + nf * 16 + r;
                float v = acc[mf][nf][rr] * sc[oc] + bi[oc];
                v = (v >= 0.f) ? v : 0.1f * v;
                y[((size_t)(b * OC + oc) * HO + oh) * WO + ow] = f2b(v);
            }
}

// ---------------------------------------------------------------------------
// 1x1 conv (192->9 logits, group g) + softmax + unfold-weighted sum (as R2).
// ---------------------------------------------------------------------------
__global__ __launch_bounds__(256) void mask_apply(
        const float* __restrict__ x, const ushort* __restrict__ y,
        const float* __restrict__ w2, float* __restrict__ out) {
    __shared__ float w2l[OC * 9];
    const int bid = blockIdx.x;
    const int g = bid % Gg;
    const int oh = (bid / Gg) % HO;
    const int b = bid / (Gg * HO);

    for (int t = threadIdx.x; t < OC * 9; t += 256) {
        const int k = t % 9;
        const int c = t / 9;
        w2l[t] = w2[(g * 9 + k) * OC + c];
    }
    __syncthreads();

    const int ow = threadIdx.x;
    float logit[9];
#pragma unroll
    for (int k = 0; k < 9; ++k) logit[k] = 0.f;

    const ushort* yp = y + ((size_t)b * OC * HO + oh) * WO + ow;
    for (int c = 0; c < OC; ++c) {
        const float yv = b2f(yp[(size_t)c * HO * WO]);
        const float* wr = &w2l[c * 9];
#pragma unroll
        for (int k = 0; k < 9; ++k) logit[k] += yv * wr[k];
    }

    float m = logit[0];
#pragma unroll
    for (int k = 1; k < 9; ++k) m = fmaxf(m, logit[k]);
    float p[9], s = 0.f;
#pragma unroll
    for (int k = 0; k < 9; ++k) { p[k] = __expf(logit[k] - m); s += p[k]; }
    const float inv = 1.f / s;
#pragma unroll
    for (int k = 0; k < 9; ++k) p[k] *= inv;

    const int iw0 = 2 * ow - 1;
    const int ih0 = 2 * oh - 1;
#pragma unroll
    for (int i = 0; i < CPG; ++i) {
        const int cc = i * Gg + g;
        const float* xp = x + ((size_t)(b * Cc + cc) * Hh) * Ww;
        float acc = 0.f;
#pragma unroll
        for (int kh = 0; kh < 3; ++kh) {
            const int ih = ih0 + kh;
            if (ih < 0) continue;
            const float* row = xp + (size_t)ih * Ww;
#pragma unroll
            for (int kw = 0; kw < 3; ++kw) {
                const int iw = iw0 + kw;
                if (iw < 0) continue;
                acc += p[kh * 3 + kw] * row[iw];
            }
        }
        out[((size_t)(b * Cc + cc) * HO + oh) * WO + ow] = acc;
    }
}

extern "C" void kernel_launch(void* const* d_in, const int* in_sizes, int n_in,
                              void* d_out, int out_size, void* d_ws, size_t ws_size,
                              hipStream_t stream) {
    const float* x     = (const float*)d_in[0];
    const float* w1    = (const float*)d_in[1];
    const float* gamma = (const float*)d_in[2];
    const float* beta  = (const float*)d_in[3];
    const float* w2    = (const float*)d_in[4];
    float* out = (float*)d_out;

    ushort* y     = (ushort*)d_ws;                              // 50,331,648 B
    ushort* apack = (ushort*)((char*)d_ws + (size_t)50331648);  // +331,776 B

    pack_w1<<<27 * 12, 64, 0, stream>>>(w1, apack);
    conv_mfma<<<Bb * HO * 2, 256, 0, stream>>>(x, apack, gamma, beta, y);
    mask_apply<<<Bb * HO * Gg, 256, 0, stream>>>(x, y, w2, out);
}

// Round 4
// 227.670 us; speedup vs baseline: 6.5828x; 1.3857x over previous
//
#include <hip/hip_runtime.h>
#include <hip/hip_bf16.h>

#define Bb 4
#define Cc 96
#define Hh 256
#define Ww 512
#define OC 192
#define HO 128
#define WO 256
#define Gg 16
#define CPG 6

typedef __attribute__((ext_vector_type(4))) float f32x4;
typedef __attribute__((ext_vector_type(8))) short bf16x8;
typedef __attribute__((ext_vector_type(4))) short bf16x4;

static __device__ __forceinline__ ushort f2b(float f) {
    __hip_bfloat16 h = __float2bfloat16(f);
    return *reinterpret_cast<ushort*>(&h);
}

// ---------------------------------------------------------------------------
// Pack w1 into MFMA fragment order (HW-verified mapping, unchanged):
// k = chunk*288 + tap*32 + icw ; slot (k0, mf, lane, j): m = mf*16+(lane&15),
// klocal = (lane>>4)*4 + (j&3) + 16*(j>>2)
// ---------------------------------------------------------------------------
__global__ __launch_bounds__(64) void pack_w1(const float* __restrict__ w1,
                                              ushort* __restrict__ apack) {
    const int blk = blockIdx.x;      // 27*12
    const int k0 = blk / 12;
    const int mf = blk % 12;
    const int lane = threadIdx.x;
    const int m = mf * 16 + (lane & 15);
    const int chunk = k0 / 9;
    const int tap = k0 % 9;
    ushort* dst = apack + (((size_t)(k0 * 12 + mf) * 64) + lane) * 8;
#pragma unroll
    for (int j = 0; j < 8; ++j) {
        const int klocal = ((lane >> 4) * 4) + (j & 3) + 16 * (j >> 2);
        const int ic = chunk * 32 + klocal;
        dst[j] = f2b(w1[(size_t)(m * Cc + ic) * 9 + tap]);
    }
}

// ---------------------------------------------------------------------------
// Pack w2 [144][192] into the same fragment scheme: 6 k-steps x 9 m-frags.
// ---------------------------------------------------------------------------
__global__ __launch_bounds__(64) void pack_w2(const float* __restrict__ w2,
                                              ushort* __restrict__ w2p) {
    const int blk = blockIdx.x;      // 6*9
    const int ks = blk / 9;
    const int mf = blk % 9;
    const int lane = threadIdx.x;
    const int m = mf * 16 + (lane & 15);
    ushort* dst = w2p + (((size_t)(ks * 9 + mf) * 64) + lane) * 8;
#pragma unroll
    for (int j = 0; j < 8; ++j) {
        const int klocal = ((lane >> 4) * 4) + (j & 3) + 16 * (j >> 2);
        const int c = ks * 32 + klocal;
        dst[j] = f2b(w2[(size_t)m * OC + c]);
    }
}

// ---------------------------------------------------------------------------
// Fully fused: conv3x3s2(96->192)+BN+LReLU (MFMA) -> y in LDS (bf16,
// transposed+swizzled) -> 1x1 conv logits (MFMA) -> softmax -> patch apply.
// Block = (b, oh, owt): 256 thr, 4 waves. LDS union: xl | yl | logits.
// ---------------------------------------------------------------------------
#define XL_HALO (3 * 2 * 128 * 32)        // 24576 ushorts
#define UNION_USHORTS 38016               // 76032 B = logits 144*132 fp32

__global__ __launch_bounds__(256, 2) void fused(
        const float* __restrict__ x, const ushort* __restrict__ apack,
        const ushort* __restrict__ w2p,
        const float* __restrict__ gamma, const float* __restrict__ beta,
        float* __restrict__ out) {
    __shared__ __align__(16) ushort smem[UNION_USHORTS];
    __shared__ float sc[OC], bi[OC];

    const int bid = blockIdx.x;
    const int owt = bid & 1;
    const int oh = (bid >> 1) & 127;
    const int b = bid >> 8;
    const int ow0 = owt * 128;
    const int tid = threadIdx.x;
    const int wid = tid >> 6;
    const int wm = wid & 1;        // conv M half: oc base = wm*96
    const int wn = wid >> 1;       // conv N half: ow base = wn*64
    const int lane = tid & 63;
    const int r = lane & 15;
    const int q = lane >> 4;

    if (tid < OC) {
        const float bnr = 1.0f / sqrtf(1.0f + 1e-5f);
        sc[tid] = gamma[tid] * bnr;
        bi[tid] = beta[tid];
    }

    f32x4 cacc[6][4];
#pragma unroll
    for (int mf = 0; mf < 6; ++mf)
#pragma unroll
        for (int nf = 0; nf < 4; ++nf) cacc[mf][nf] = (f32x4){0.f, 0.f, 0.f, 0.f};

    const size_t chs = (size_t)Hh * Ww;

    // ================= conv phase (R3-verified) =================
    for (int chunk = 0; chunk < 3; ++chunk) {
        __syncthreads();
        const int icc = chunk * 32;
#pragma unroll
        for (int it = 0; it < 12; ++it) {
            const int gg = tid + (it << 8);
            const int oct = gg & 3;
            const int col = (gg >> 2) & 127;
            const int par = (gg >> 9) & 1;
            const int row = gg >> 10;
            const int ih = 2 * oh - 1 + row;
            const int gcol = 2 * (ow0 + col) + par;
            float v[8];
            if (ih >= 0) {
                const float* xp = x + ((size_t)(b * Cc + icc + (oct << 3)) * Hh + ih) * Ww + gcol;
#pragma unroll
                for (int j = 0; j < 8; ++j) v[j] = xp[(size_t)j * chs];
            } else {
#pragma unroll
                for (int j = 0; j < 8; ++j) v[j] = 0.f;
            }
            bf16x8 u;
#pragma unroll
            for (int j = 0; j < 8; ++j) u[j] = (short)f2b(v[j]);
            const int du = ((row * 2 + par) * 128 + col) * 32 + ((oct ^ (col & 3)) << 3);
            *reinterpret_cast<bf16x8*>(smem + du) = u;
        }
        if (tid < 12) {
            const int oct = tid & 3;
            const int row = tid >> 2;
            const int ih = 2 * oh - 1 + row;
            const int gcol = 2 * ow0 - 1;
            float v[8];
            if (ih >= 0 && gcol >= 0) {
                const float* xp = x + ((size_t)(b * Cc + icc + (oct << 3)) * Hh + ih) * Ww + gcol;
#pragma unroll
                for (int j = 0; j < 8; ++j) v[j] = xp[(size_t)j * chs];
            } else {
#pragma unroll
                for (int j = 0; j < 8; ++j) v[j] = 0.f;
            }
            bf16x8 u;
#pragma unroll
            for (int j = 0; j < 8; ++j) u[j] = (short)f2b(v[j]);
            *reinterpret_cast<bf16x8*>(smem + XL_HALO + row * 32 + (oct << 3)) = u;
        }
        __syncthreads();

#pragma unroll
        for (int tap = 0; tap < 9; ++tap) {
            const int kh = tap / 3, kw = tap % 3;
            const int par = (kw == 1) ? 0 : 1;
            const int cb = (kw == 0) ? -1 : 0;
            const int k0 = chunk * 9 + tap;

            bf16x8 af[6];
            const ushort* ap = apack + (((size_t)(k0 * 12 + wm * 6) * 64) + lane) * 8;
#pragma unroll
            for (int mf = 0; mf < 6; ++mf)
                af[mf] = *reinterpret_cast<const bf16x8*>(ap + (size_t)mf * 64 * 8);

            bf16x8 bfr[4];
#pragma unroll
            for (int nf = 0; nf < 4; ++nf) {
                const int n = wn * 64 + nf * 16 + r;
                const int colc = n + cb;
                int lo_u, hi_u;
                if (colc >= 0) {
                    const int bu = ((kh * 2 + par) * 128 + colc) * 32;
                    const int sw = colc & 3;
                    lo_u = bu + ((((q >> 1)) ^ sw) << 3) + ((q & 1) << 2);
                    hi_u = bu + (((2 + (q >> 1)) ^ sw) << 3) + ((q & 1) << 2);
                } else {
                    const int bu = XL_HALO + kh * 32;
                    lo_u = bu + (q << 2);
                    hi_u = bu + 16 + (q << 2);
                }
                bf16x4 lo = *reinterpret_cast<const bf16x4*>(smem + lo_u);
                bf16x4 hi = *reinterpret_cast<const bf16x4*>(smem + hi_u);
                bf16x8 t;
                t[0] = lo[0]; t[1] = lo[1]; t[2] = lo[2]; t[3] = lo[3];
                t[4] = hi[0]; t[5] = hi[1]; t[6] = hi[2]; t[7] = hi[3];
                bfr[nf] = t;
            }
#pragma unroll
            for (int mf = 0; mf < 6; ++mf)
#pragma unroll
                for (int nf = 0; nf < 4; ++nf)
                    cacc[mf][nf] = __builtin_amdgcn_mfma_f32_16x16x32_bf16(
                        af[mf], bfr[nf], cacc[mf][nf], 0, 0, 0);
        }
    }

    // ============ epilogue: BN+LReLU -> yl[ow][c] bf16, swizzled ============
    __syncthreads();   // all waves done reading xl
#pragma unroll
    for (int mf = 0; mf < 6; ++mf) {
        const int cbase = wm * 96 + mf * 16;     // + q*4 + rr
        const int cb3 = cbase >> 3;              // unit base (q>>1 added below)
#pragma unroll
        for (int nf = 0; nf < 4; ++nf) {
            const int ow = wn * 64 + nf * 16 + r;
            ushort pk[4];
#pragma unroll
            for (int rr = 0; rr < 4; ++rr) {
                const int oc = cbase + q * 4 + rr;
                float v = cacc[mf][nf][rr] * sc[oc] + bi[oc];
                v = (v >= 0.f) ? v : 0.1f * v;
                pk[rr] = f2b(v);
            }
            const int u = cb3 + (q >> 1);
            const int us = (u ^ (ow & 7)) * 8 + (q & 1) * 4;
            *reinterpret_cast<bf16x4*>(smem + ow * 192 + us) =
                *reinterpret_cast<bf16x4*>(pk);
        }
    }
    __syncthreads();

    // ============ logits MFMA: [144][128] = w2[144x192] * yl ============
    f32x4 macc[9][2];
#pragma unroll
    for (int mf = 0; mf < 9; ++mf)
#pragma unroll
        for (int nf = 0; nf < 2; ++nf) macc[mf][nf] = (f32x4){0.f, 0.f, 0.f, 0.f};

#pragma unroll
    for (int ks = 0; ks < 6; ++ks) {
        bf16x8 af[9];
        const ushort* ap = w2p + (((size_t)(ks * 9) * 64) + lane) * 8;
#pragma unroll
        for (int mf = 0; mf < 9; ++mf)
            af[mf] = *reinterpret_cast<const bf16x8*>(ap + (size_t)mf * 64 * 8);
        bf16x8 bfr[2];
#pragma unroll
        for (int nf = 0; nf < 2; ++nf) {
            const int ow = wid * 32 + nf * 16 + r;
            const ushort* base = smem + ow * 192;
            const int swz = r & 7;
            const int ul = ((ks * 4 + (q >> 1)) ^ swz) * 8 + (q & 1) * 4;
            const int uh = ((ks * 4 + 2 + (q >> 1)) ^ swz) * 8 + (q & 1) * 4;
            bf16x4 lo = *reinterpret_cast<const bf16x4*>(base + ul);
            bf16x4 hi = *reinterpret_cast<const bf16x4*>(base + uh);
            bf16x8 t;
            t[0] = lo[0]; t[1] = lo[1]; t[2] = lo[2]; t[3] = lo[3];
            t[4] = hi[0]; t[5] = hi[1]; t[6] = hi[2]; t[7] = hi[3];
            bfr[nf] = t;
        }
#pragma unroll
        for (int mf = 0; mf < 9; ++mf)
#pragma unroll
            for (int nf = 0; nf < 2; ++nf)
                macc[mf][nf] = __builtin_amdgcn_mfma_f32_16x16x32_bf16(
                    af[mf], bfr[nf], macc[mf][nf], 0, 0, 0);
    }
    __syncthreads();   // yl reads done before overwriting with logits

    // ============ dump logits fp32 [144][132] ============
    float* lg = reinterpret_cast<float*>(smem);
#pragma unroll
    for (int mf = 0; mf < 9; ++mf)
#pragma unroll
        for (int nf = 0; nf < 2; ++nf) {
            const int n = wid * 32 + nf * 16 + r;
#pragma unroll
            for (int rr = 0; rr < 4; ++rr) {
                const int m = mf * 16 + q * 4 + rr;
                lg[m * 132 + n] = macc[mf][nf][rr];
            }
        }
    __syncthreads();

    // ============ softmax + patch apply ============
    const int ih0 = 2 * oh - 1;
#pragma unroll
    for (int it = 0; it < 8; ++it) {
        const int idx = (it << 8) + tid;
        const int g = idx >> 7;
        const int owl = idx & 127;
        const int owg = ow0 + owl;

        float lgv[9];
#pragma unroll
        for (int k = 0; k < 9; ++k) lgv[k] = lg[(g * 9 + k) * 132 + owl];
        float mx = lgv[0];
#pragma unroll
        for (int k = 1; k < 9; ++k) mx = fmaxf(mx, lgv[k]);
        float p[9], s = 0.f;
#pragma unroll
        for (int k = 0; k < 9; ++k) { p[k] = __expf(lgv[k] - mx); s += p[k]; }
        const float inv = 1.f / s;
#pragma unroll
        for (int k = 0; k < 9; ++k) p[k] *= inv;

        const int iw0 = 2 * owg - 1;
        const bool okh0 = (oh > 0);
        const bool okw0 = (owg > 0);
#pragma unroll
        for (int i = 0; i < CPG; ++i) {
            const int cc = i * Gg + g;
            const float* xc = x + (size_t)(b * Cc + cc) * chs;
            float acc = 0.f;
#pragma unroll
            for (int kh = 0; kh < 3; ++kh) {
                if (kh == 0 && !okh0) continue;
                const float* rowp = xc + (size_t)(ih0 + kh) * Ww + iw0;
                if (okw0) acc += p[kh * 3 + 0] * rowp[0];
                acc += p[kh * 3 + 1] * rowp[1];
                acc += p[kh * 3 + 2] * rowp[2];
            }
            out[((size_t)(b * Cc + cc) * HO + oh) * WO + owg] = acc;
        }
    }
}

extern "C" void kernel_launch(void* const* d_in, const int* in_sizes, int n_in,
                              void* d_out, int out_size, void* d_ws, size_t ws_size,
                              hipStream_t stream) {
    const float* x     = (const float*)d_in[0];
    const float* w1    = (const float*)d_in[1];
    const float* gamma = (const float*)d_in[2];
    const float* beta  = (const float*)d_in[3];
    const float* w2    = (const float*)d_in[4];
    float* out = (float*)d_out;

    ushort* apack = (ushort*)d_ws;                           // 331,776 B
    ushort* w2p   = (ushort*)((char*)d_ws + 331776);         // + 55,296 B

    pack_w1<<<27 * 12, 64, 0, stream>>>(w1, apack);
    pack_w2<<<6 * 9, 64, 0, stream>>>(w2, w2p);
    fused<<<Bb * HO * 2, 256, 0, stream>>>(x, apack, w2p, gamma, beta, out);
}